// Round 9
// baseline (144.929 us; speedup 1.0000x reference)
//
#include <hip/hip_runtime.h>

// Hough voting (PoseCNN-style), round 9 — ATTRIBUTION SPLIT.
// r4..r8 all floor at ~110us with every pipe <25% busy; four bottleneck
// theories (gather, occupancy, LDS regroup, cursor chains) tested null.
// This round splits emit into two REAL kernels so rocprof attributes time:
//   emitA = front-end (gather+ray) + pass-A row counts + cursor reserve
//           + publish per-(block,row) global bases (gbTable, 2.4MB)
//   emitB = front-end recomputed (identical FP sequence -> identical votes)
//           + pass-B s_rel LDS atomics + scattered u16 stores
// Algebra vs r8's fused emit (112us): F = A+B-112; passA+cur = A-F;
// passB+stores = B-F. Output unchanged/correct.

#define MAXC 32
#define NSEG 4

__device__ __forceinline__ void ray_setup(
    const int* __restrict__ label, const float* __restrict__ vertex,
    int C, int HW, int W, int b, int p,
    int& lab, float& z, bool& fg,
    float& nxn, float& nyn, float& xs, float& ys)
{
    lab = label[(size_t)b * HW + p];
    const float* vb = vertex + ((size_t)(b * 3 * C + 3 * lab)) * HW + p;
    float nx = vb[0];
    float ny = vb[(size_t)HW];
    z = vb[2 * (size_t)HW];
    fg = false;
    nxn = 0.f; nyn = 0.f; xs = 0.f; ys = 0.f;
    if (lab > 0) {
        fg = true;
        // Match XLA f32 exactly: no FMA contraction, IEEE sqrt/div, RNE round.
        float nrm = __fsqrt_rn(__fadd_rn(__fmul_rn(nx, nx), __fmul_rn(ny, ny)));
        float inv = __fdiv_rn(1.0f, __fadd_rn(nrm, 1e-8f));
        nxn = __fmul_rn(nx, inv);
        nyn = __fmul_rn(ny, inv);
        xs = (float)(p % W);
        ys = (float)(p / W);
    }
}

__global__ __launch_bounds__(512) void emitA_kernel(
    const int* __restrict__ label, const float* __restrict__ vertex,
    unsigned* __restrict__ cursor, unsigned* __restrict__ gbTable,
    unsigned* __restrict__ cnt, float* __restrict__ zsum,
    int C, int H, int W, int HW, int NB)
{
    __shared__ unsigned s_bin[512];   // votes per destination row
    __shared__ unsigned s_ccnt[MAXC];
    __shared__ float s_cz[MAXC];

    int tid = threadIdx.x;
    int b = blockIdx.y;
    int p = blockIdx.x * 512 + tid;
    int seg = blockIdx.x & (NSEG - 1);

    s_bin[tid] = 0u;
    if (tid < MAXC) { s_ccnt[tid] = 0u; s_cz[tid] = 0.0f; }
    __syncthreads();

    if (p < HW) {
        int lab; float z; bool fg; float nxn, nyn, xs, ys;
        ray_setup(label, vertex, C, HW, W, b, p, lab, z, fg, nxn, nyn, xs, ys);
        atomicAdd(&s_ccnt[lab], 1u);
        atomicAdd(&s_cz[lab], z);
        if (fg) {
            #pragma unroll
            for (int i = 1; i <= 32; ++i) {
                float t = (float)i * 4.0f;
                int px = (int)rintf(__fadd_rn(xs, __fmul_rn(nxn, t)));
                int py = (int)rintf(__fadd_rn(ys, __fmul_rn(nyn, t)));
                if (px >= 0 && px < W && py >= 0 && py < H)
                    atomicAdd(&s_bin[py], 1u);
            }
        }
    }
    __syncthreads();

    // Reserve range in this block's segment; publish base for emitB.
    if (tid < H) {
        unsigned n = s_bin[tid];
        unsigned base = n ? atomicAdd(&cursor[seg * NB + b * H + tid], n) : 0u;
        gbTable[(size_t)(b * gridDim.x + blockIdx.x) * 512 + tid] = base;
    }

    if (tid < C) {
        unsigned c = s_ccnt[tid];
        if (c) {
            atomicAdd(&cnt[b * C + tid], c);
            atomicAdd(&zsum[b * C + tid], s_cz[tid]);
        }
    }
}

__global__ __launch_bounds__(512) void emitB_kernel(
    const int* __restrict__ label, const float* __restrict__ vertex,
    const unsigned* __restrict__ gbTable, unsigned short* __restrict__ bucketData,
    int C, int H, int W, int HW, int SEGCAP, int NB)
{
    __shared__ unsigned s_rel[512];   // block-local write offset per row
    __shared__ unsigned s_gb[512];    // global base per row (this block's seg)

    int tid = threadIdx.x;
    int b = blockIdx.y;
    int p = blockIdx.x * 512 + tid;
    int seg = blockIdx.x & (NSEG - 1);

    s_rel[tid] = 0u;
    s_gb[tid] = gbTable[(size_t)(b * gridDim.x + blockIdx.x) * 512 + tid];
    __syncthreads();

    if (p < HW) {
        int lab; float z; bool fg; float nxn, nyn, xs, ys;
        ray_setup(label, vertex, C, HW, W, b, p, lab, z, fg, nxn, nyn, xs, ys);
        if (fg) {
            unsigned labsh = (unsigned)lab << 10;
            #pragma unroll
            for (int i = 1; i <= 32; ++i) {
                float t = (float)i * 4.0f;
                int px = (int)rintf(__fadd_rn(xs, __fmul_rn(nxn, t)));
                int py = (int)rintf(__fadd_rn(ys, __fmul_rn(nyn, t)));
                if (px >= 0 && px < W && py >= 0 && py < H) {
                    unsigned rel = atomicAdd(&s_rel[py], 1u);
                    unsigned g = s_gb[py] + rel;
                    if (g < (unsigned)SEGCAP)
                        bucketData[((size_t)(b * H + py) * NSEG + seg) * SEGCAP + g] =
                            (unsigned short)(labsh | (unsigned)px);
                }
            }
        }
    }
}

__global__ __launch_bounds__(256) void hist_kernel(
    const unsigned short* __restrict__ bucketData,
    const unsigned* __restrict__ cursor,
    unsigned long long* __restrict__ keys,
    int C, int H, int W, int SEGCAP, int NB)
{
    extern __shared__ char sm[];
    unsigned* hist = (unsigned*)sm;   // C*W/2 words, u16 pair per word
    unsigned long long* s_wb =
        (unsigned long long*)(sm + (size_t)(C * W / 2) * 4);  // C*4 wave bests

    int tid = threadIdx.x;
    int lane = tid & 63, wave = tid >> 6;
    int py = blockIdx.x;
    int b = blockIdx.y;
    int words = C * W / 2;

    for (int i = tid; i < words; i += 256) hist[i] = 0u;
    __syncthreads();

    int bucket = b * H + py;
    #pragma unroll
    for (int seg = 0; seg < NSEG; ++seg) {
        unsigned n = cursor[seg * NB + bucket];
        if (n > (unsigned)SEGCAP) n = (unsigned)SEGCAP;
        const unsigned short* src =
            bucketData + ((size_t)bucket * NSEG + seg) * SEGCAP;
        for (unsigned i = tid; i < n; i += 256) {
            unsigned r = src[i];
            unsigned idx = (r >> 10) * (unsigned)W + (r & 1023u);  // c*W+px
            atomicAdd(&hist[idx >> 1], 1u << ((idx & 1u) * 16));   // packed u16
        }
    }
    __syncthreads();

    // Per-class argmax over ALL cells of this row (zero counts included so
    // global tie-break == jnp.argmax: max count, then min flat index).
    unsigned rowbase = (unsigned)py * (unsigned)W;
    for (int c = 0; c < C; ++c) {
        unsigned long long best = 0;
        for (int px = tid; px < W; px += 256) {
            unsigned cv = (hist[(unsigned)(c * W + px) >> 1] >> ((px & 1) * 16)) & 0xFFFFu;
            unsigned long long k = ((unsigned long long)cv << 32)
                                 | (unsigned long long)(0xFFFFFFFFu - (rowbase + px));
            if (k > best) best = k;
        }
        #pragma unroll
        for (int off = 32; off > 0; off >>= 1) {
            unsigned long long o = __shfl_xor(best, off, 64);
            if (o > best) best = o;
        }
        if (lane == 0) s_wb[c * 4 + wave] = best;
    }
    __syncthreads();
    if (tid < C) {
        unsigned long long m = s_wb[tid * 4];
        #pragma unroll
        for (int w2 = 1; w2 < 4; ++w2)
            if (s_wb[tid * 4 + w2] > m) m = s_wb[tid * 4 + w2];
        atomicMax(&keys[b * C + tid], m);
    }
}

__global__ void finalize_kernel(const unsigned long long* __restrict__ keys,
                                const unsigned* __restrict__ cnt,
                                const float* __restrict__ zsum,
                                const float* __restrict__ extents,
                                const float* __restrict__ meta,
                                float* __restrict__ out,
                                int B, int C, int W)
{
    int i = threadIdx.x;
    if (i >= B * C) return;
    int b = i / C, c = i % C;
    unsigned long long k = keys[i];
    unsigned votes = (unsigned)(k >> 32);
    unsigned peak = 0xFFFFFFFFu - (unsigned)(k & 0xFFFFFFFFull);
    float cx = (float)(peak % (unsigned)W);
    float cy = (float)(peak / (unsigned)W);
    float n = (float)cnt[i];
    float depth = zsum[i] / fmaxf(n, 1.0f);
    float fx = meta[b * 9 + 0];
    const float* e = extents + c * 3;
    float diag = sqrtf(e[0] * e[0] + e[1] * e[1] + e[2] * e[2]);
    float half = 0.5f * diag * fx / fmaxf(fabsf(depth), 0.001f);
    float* o = out + (size_t)i * 9;
    o[0] = (float)c;
    o[1] = (float)votes;
    o[2] = cx - half;
    o[3] = cy - half;
    o[4] = cx + half;
    o[5] = cy + half;
    o[6] = cx;
    o[7] = cy;
    o[8] = depth;
}

extern "C" void kernel_launch(void* const* d_in, const int* in_sizes, int n_in,
                              void* d_out, int out_size, void* d_ws, size_t ws_size,
                              hipStream_t stream)
{
    const int* label    = (const int*)d_in[0];
    const float* vertex = (const float*)d_in[1];
    const float* extents= (const float*)d_in[2];
    const float* meta   = (const float*)d_in[3];
    // d_in[4] = gt (unused), d_in[5] = is_train (unused)

    int C = in_sizes[2] / 3;      // extents: C*3
    int B = in_sizes[3] / 9;      // meta: B*9
    int HW = in_sizes[0] / B;     // label: B*H*W
    const int W = 640;
    int H = HW / W;
    int NB = B * H;               // number of row buckets
    int GX = (HW + 511) / 512;    // emit grid x

    // Workspace: keys | cursor (NSEG*NB) | cnt | zsum | gbTable | pad | bucketData
    size_t keysOff = 0;
    size_t curOff  = keysOff + (size_t)B * C * 8;
    size_t cntOff  = curOff + (size_t)NSEG * NB * 4;
    size_t zsumOff = cntOff + (size_t)B * C * 4;
    size_t zeroEnd = zsumOff + (size_t)B * C * 4;
    size_t gbOff   = (zeroEnd + 63) & ~(size_t)63;
    size_t gbBytes = (size_t)B * GX * 512 * 4;
    size_t dataOff = (gbOff + gbBytes + 63) & ~(size_t)63;

    // Adaptive per-segment capacity (records are u16).
    size_t availRec = (ws_size > dataOff) ? (ws_size - dataOff) / ((size_t)NB * NSEG * 2) : 0;
    int SEGCAP = (int)(availRec > 8192 ? 8192 : availRec);
    SEGCAP &= ~63;

    unsigned long long* keys = (unsigned long long*)((char*)d_ws + keysOff);
    unsigned* cursor         = (unsigned*)((char*)d_ws + curOff);
    unsigned* cnt            = (unsigned*)((char*)d_ws + cntOff);
    float* zsum              = (float*)((char*)d_ws + zsumOff);
    unsigned* gbTable        = (unsigned*)((char*)d_ws + gbOff);
    unsigned short* bucketData = (unsigned short*)((char*)d_ws + dataOff);

    hipMemsetAsync(d_ws, 0, zeroEnd, stream);

    dim3 egrid(GX, B);
    emitA_kernel<<<egrid, 512, 0, stream>>>(label, vertex, cursor, gbTable,
                                            cnt, zsum, C, H, W, HW, NB);
    emitB_kernel<<<egrid, 512, 0, stream>>>(label, vertex, gbTable, bucketData,
                                            C, H, W, HW, SEGCAP, NB);

    dim3 hgrid(H, B);
    size_t hsm = (size_t)(C * W / 2) * 4 + (size_t)C * 4 * 8;
    hist_kernel<<<hgrid, 256, hsm, stream>>>(bucketData, cursor, keys, C, H, W, SEGCAP, NB);

    finalize_kernel<<<1, 64, 0, stream>>>(keys, cnt, zsum, extents, meta,
                                          (float*)d_out, B, C, W);
}

// Round 10
// 121.219 us; speedup vs baseline: 1.1956x; 1.1956x over previous
//
#include <hip/hip_runtime.h>

// Hough voting (PoseCNN-style), round 10.
// label (B,H,W) i32; vertex (B,3C,H,W) f32; extents (C,3); meta (B,9);
// out (B,C,9) f32. B=2,C=22,H=480,W=640. Assumes H <= 512, C < 32.
//
// r10 change: r7/r8's emit reported VGPR_Count=24 while holding a vote[32]
// per-thread array -> the array was SCRATCH-SPILLED (dynamic indexing in a
// not-fully-unrolled consumer loop forces local memory). 19.6M x2 scratch
// round-trips serialized inside each block = the invisible ~90us floor.
// Fix: no vote array at all -- recompute the ray math in pass B (identical
// FP sequence -> identical px/py). Everything else identical to r8.

#define MAXC 32
#define NSEG 4

__global__ __launch_bounds__(512) void emit_kernel(
    const int* __restrict__ label, const float* __restrict__ vertex,
    unsigned short* __restrict__ bucketData, unsigned* __restrict__ cursor,
    unsigned* __restrict__ cnt, float* __restrict__ zsum,
    int C, int H, int W, int HW, int SEGCAP, int NB)
{
    __shared__ unsigned s_bin[512];   // votes per destination row
    __shared__ unsigned s_rel[512];   // block-local write offset per row
    __shared__ unsigned s_gb[512];    // global base per row (this block's seg)
    __shared__ unsigned s_ccnt[MAXC];
    __shared__ float s_cz[MAXC];

    int tid = threadIdx.x;
    int b = blockIdx.y;
    int p = blockIdx.x * 512 + tid;
    int seg = blockIdx.x & (NSEG - 1);

    s_bin[tid] = 0u;
    s_rel[tid] = 0u;
    if (tid < MAXC) { s_ccnt[tid] = 0u; s_cz[tid] = 0.0f; }
    __syncthreads();

    int lab = 0;
    bool fg = false;
    float nxn = 0.f, nyn = 0.f, xs = 0.f, ys = 0.f;
    if (p < HW) {
        lab = label[(size_t)b * HW + p];
        const float* vb = vertex + ((size_t)(b * 3 * C + 3 * lab)) * HW + p;
        float nx = vb[0];
        float ny = vb[(size_t)HW];
        float z  = vb[2 * (size_t)HW];
        atomicAdd(&s_ccnt[lab], 1u);
        atomicAdd(&s_cz[lab], z);
        if (lab > 0) {
            fg = true;
            // Match XLA f32 exactly: no FMA contraction, IEEE sqrt/div, RNE round.
            float nrm = __fsqrt_rn(__fadd_rn(__fmul_rn(nx, nx), __fmul_rn(ny, ny)));
            float inv = __fdiv_rn(1.0f, __fadd_rn(nrm, 1e-8f));
            nxn = __fmul_rn(nx, inv);
            nyn = __fmul_rn(ny, inv);
            xs = (float)(p % W);
            ys = (float)(p / W);
        }
    }

    // Pass A: count votes per destination row. Scalars only -- no per-thread
    // array anywhere in this kernel.
    if (fg) {
        #pragma unroll
        for (int i = 1; i <= 32; ++i) {
            float t = (float)i * 4.0f;
            int px = (int)rintf(__fadd_rn(xs, __fmul_rn(nxn, t)));
            int py = (int)rintf(__fadd_rn(ys, __fmul_rn(nyn, t)));
            if (px >= 0 && px < W && py >= 0 && py < H)
                atomicAdd(&s_bin[py], 1u);
        }
    }
    __syncthreads();

    // Reserve range in this block's segment of each row bucket (parallel,
    // one atomic per non-empty row; 4-way segmented to cut chains).
    if (tid < H) {
        unsigned n = s_bin[tid];
        s_gb[tid] = n ? atomicAdd(&cursor[seg * NB + b * H + tid], n) : 0u;
    }
    __syncthreads();

    // Pass B: recompute votes (identical FP sequence) and write directly to
    // the segment of the global row bucket.
    if (fg) {
        unsigned labsh = (unsigned)lab << 10;
        #pragma unroll
        for (int i = 1; i <= 32; ++i) {
            float t = (float)i * 4.0f;
            int px = (int)rintf(__fadd_rn(xs, __fmul_rn(nxn, t)));
            int py = (int)rintf(__fadd_rn(ys, __fmul_rn(nyn, t)));
            if (px >= 0 && px < W && py >= 0 && py < H) {
                unsigned rel = atomicAdd(&s_rel[py], 1u);
                unsigned g = s_gb[py] + rel;
                if (g < (unsigned)SEGCAP)
                    bucketData[((size_t)(b * H + py) * NSEG + seg) * SEGCAP + g] =
                        (unsigned short)(labsh | (unsigned)px);
            }
        }
    }

    // Class aggregates.
    if (tid < C) {
        unsigned c = s_ccnt[tid];
        if (c) {
            atomicAdd(&cnt[b * C + tid], c);
            atomicAdd(&zsum[b * C + tid], s_cz[tid]);
        }
    }
}

__global__ __launch_bounds__(256) void hist_kernel(
    const unsigned short* __restrict__ bucketData,
    const unsigned* __restrict__ cursor,
    unsigned long long* __restrict__ keys,
    int C, int H, int W, int SEGCAP, int NB)
{
    extern __shared__ char sm[];
    unsigned* hist = (unsigned*)sm;   // C*W/2 words, u16 pair per word
    unsigned long long* s_wb =
        (unsigned long long*)(sm + (size_t)(C * W / 2) * 4);  // C*4 wave bests

    int tid = threadIdx.x;
    int lane = tid & 63, wave = tid >> 6;
    int py = blockIdx.x;
    int b = blockIdx.y;
    int words = C * W / 2;

    for (int i = tid; i < words; i += 256) hist[i] = 0u;
    __syncthreads();

    int bucket = b * H + py;
    #pragma unroll
    for (int seg = 0; seg < NSEG; ++seg) {
        unsigned n = cursor[seg * NB + bucket];
        if (n > (unsigned)SEGCAP) n = (unsigned)SEGCAP;
        const unsigned short* src =
            bucketData + ((size_t)bucket * NSEG + seg) * SEGCAP;
        for (unsigned i = tid; i < n; i += 256) {
            unsigned r = src[i];
            unsigned idx = (r >> 10) * (unsigned)W + (r & 1023u);  // c*W+px
            atomicAdd(&hist[idx >> 1], 1u << ((idx & 1u) * 16));   // packed u16
        }
    }
    __syncthreads();

    // Per-class argmax over ALL cells of this row (zero counts included so
    // global tie-break == jnp.argmax: max count, then min flat index).
    unsigned rowbase = (unsigned)py * (unsigned)W;
    for (int c = 0; c < C; ++c) {
        unsigned long long best = 0;
        for (int px = tid; px < W; px += 256) {
            unsigned cv = (hist[(unsigned)(c * W + px) >> 1] >> ((px & 1) * 16)) & 0xFFFFu;
            unsigned long long k = ((unsigned long long)cv << 32)
                                 | (unsigned long long)(0xFFFFFFFFu - (rowbase + px));
            if (k > best) best = k;
        }
        #pragma unroll
        for (int off = 32; off > 0; off >>= 1) {
            unsigned long long o = __shfl_xor(best, off, 64);
            if (o > best) best = o;
        }
        if (lane == 0) s_wb[c * 4 + wave] = best;
    }
    __syncthreads();
    if (tid < C) {
        unsigned long long m = s_wb[tid * 4];
        #pragma unroll
        for (int w2 = 1; w2 < 4; ++w2)
            if (s_wb[tid * 4 + w2] > m) m = s_wb[tid * 4 + w2];
        atomicMax(&keys[b * C + tid], m);
    }
}

__global__ void finalize_kernel(const unsigned long long* __restrict__ keys,
                                const unsigned* __restrict__ cnt,
                                const float* __restrict__ zsum,
                                const float* __restrict__ extents,
                                const float* __restrict__ meta,
                                float* __restrict__ out,
                                int B, int C, int W)
{
    int i = threadIdx.x;
    if (i >= B * C) return;
    int b = i / C, c = i % C;
    unsigned long long k = keys[i];
    unsigned votes = (unsigned)(k >> 32);
    unsigned peak = 0xFFFFFFFFu - (unsigned)(k & 0xFFFFFFFFull);
    float cx = (float)(peak % (unsigned)W);
    float cy = (float)(peak / (unsigned)W);
    float n = (float)cnt[i];
    float depth = zsum[i] / fmaxf(n, 1.0f);
    float fx = meta[b * 9 + 0];
    const float* e = extents + c * 3;
    float diag = sqrtf(e[0] * e[0] + e[1] * e[1] + e[2] * e[2]);
    float half = 0.5f * diag * fx / fmaxf(fabsf(depth), 0.001f);
    float* o = out + (size_t)i * 9;
    o[0] = (float)c;
    o[1] = (float)votes;
    o[2] = cx - half;
    o[3] = cy - half;
    o[4] = cx + half;
    o[5] = cy + half;
    o[6] = cx;
    o[7] = cy;
    o[8] = depth;
}

extern "C" void kernel_launch(void* const* d_in, const int* in_sizes, int n_in,
                              void* d_out, int out_size, void* d_ws, size_t ws_size,
                              hipStream_t stream)
{
    const int* label    = (const int*)d_in[0];
    const float* vertex = (const float*)d_in[1];
    const float* extents= (const float*)d_in[2];
    const float* meta   = (const float*)d_in[3];
    // d_in[4] = gt (unused), d_in[5] = is_train (unused)

    int C = in_sizes[2] / 3;      // extents: C*3
    int B = in_sizes[3] / 9;      // meta: B*9
    int HW = in_sizes[0] / B;     // label: B*H*W
    const int W = 640;
    int H = HW / W;
    int NB = B * H;               // number of row buckets

    // Workspace: keys (u64) | cursor (u32 x NSEG*NB) | cnt | zsum | pad | bucketData
    size_t keysOff = 0;
    size_t curOff  = keysOff + (size_t)B * C * 8;
    size_t cntOff  = curOff + (size_t)NSEG * NB * 4;
    size_t zsumOff = cntOff + (size_t)B * C * 4;
    size_t zeroEnd = zsumOff + (size_t)B * C * 4;
    size_t dataOff = (zeroEnd + 63) & ~(size_t)63;

    // Adaptive per-segment capacity (records are u16).
    size_t availRec = (ws_size > dataOff) ? (ws_size - dataOff) / ((size_t)NB * NSEG * 2) : 0;
    int SEGCAP = (int)(availRec > 8192 ? 8192 : availRec);
    SEGCAP &= ~63;

    unsigned long long* keys = (unsigned long long*)((char*)d_ws + keysOff);
    unsigned* cursor         = (unsigned*)((char*)d_ws + curOff);
    unsigned* cnt            = (unsigned*)((char*)d_ws + cntOff);
    float* zsum              = (float*)((char*)d_ws + zsumOff);
    unsigned short* bucketData = (unsigned short*)((char*)d_ws + dataOff);

    hipMemsetAsync(d_ws, 0, zeroEnd, stream);

    dim3 egrid((HW + 511) / 512, B);
    emit_kernel<<<egrid, 512, 0, stream>>>(label, vertex, bucketData, cursor,
                                           cnt, zsum, C, H, W, HW, SEGCAP, NB);

    dim3 hgrid(H, B);
    size_t hsm = (size_t)(C * W / 2) * 4 + (size_t)C * 4 * 8;
    hist_kernel<<<hgrid, 256, hsm, stream>>>(bucketData, cursor, keys, C, H, W, SEGCAP, NB);

    finalize_kernel<<<1, 64, 0, stream>>>(keys, cnt, zsum, extents, meta,
                                          (float*)d_out, B, C, W);
}